// Round 7
// baseline (782.079 us; speedup 1.0000x reference)
//
#include <hip/hip_runtime.h>

#define NN 50000
#define NE 400000
#define DIM 256
#define HID 512
#define NL 5
#define BN_EPS 1e-5f
#define NB_SCAN 196   // ceil(NN/256)

typedef float float4v __attribute__((ext_vector_type(4)));
typedef _Float16 half8 __attribute__((ext_vector_type(8)));
typedef _Float16 half4v __attribute__((ext_vector_type(4)));

__device__ __forceinline__ void gl_lds16(const void* g, void* l) {
    __builtin_amdgcn_global_load_lds((__attribute__((address_space(1))) void*)g,
                                     (__attribute__((address_space(3))) void*)l, 16, 0, 0);
}

// ---------------- setup kernels ----------------

__global__ void k_zero(int* p, int n) {
    int i = blockIdx.x * blockDim.x + threadIdx.x;
    if (i < n) p[i] = 0;
}

__global__ void k_x2h(const float* __restrict__ x, _Float16* __restrict__ xh) {
    int i = blockIdx.x * blockDim.x + threadIdx.x;
    if (i >= NN * DIM / 4) return;
    float4 v = ((const float4*)x)[i];
    half4v o;
    o.x = (_Float16)v.x; o.y = (_Float16)v.y; o.z = (_Float16)v.z; o.w = (_Float16)v.w;
    ((half4v*)xh)[i] = o;
}

// C[l][a*3+b][c] = E1[l][a][c] + E2[l][b][c]
__global__ void k_ctab(const float* __restrict__ E1, const float* __restrict__ E2,
                       float* __restrict__ C) {
    int b = blockIdx.x;            // 0..44
    int l = b / 9, ab = b % 9;
    int a = ab / 3, bb = ab % 3;
    int c = threadIdx.x;
    C[(size_t)b * DIM + c] = E1[(size_t)(l * 6 + a) * DIM + c] + E2[(size_t)(l * 3 + bb) * DIM + c];
}

__global__ void k_hist(const int* __restrict__ ei, int* __restrict__ counts) {
    int e = blockIdx.x * blockDim.x + threadIdx.x;
    if (e < NE) atomicAdd(&counts[ei[NE + e]], 1);
}

// ---- multi-block coalesced exclusive scan of counts -> row_ptr/cursor ----
__global__ void k_bsum(const int* __restrict__ counts, int* __restrict__ bsum) {
    __shared__ int s[256];
    int t = threadIdx.x;
    int i = blockIdx.x * 256 + t;
    s[t] = (i < NN) ? counts[i] : 0;
    __syncthreads();
    for (int off = 128; off > 0; off >>= 1) {
        if (t < off) s[t] += s[t + off];
        __syncthreads();
    }
    if (t == 0) bsum[blockIdx.x] = s[0];
}

__global__ void k_bscan(const int* __restrict__ bsum, int* __restrict__ bofs) {
    __shared__ int s[256];
    int t = threadIdx.x;
    int v = (t < NB_SCAN) ? bsum[t] : 0;
    s[t] = v;
    __syncthreads();
    for (int off = 1; off < 256; off <<= 1) {
        int u = (t >= off) ? s[t - off] : 0;
        __syncthreads();
        s[t] += u;
        __syncthreads();
    }
    if (t < NB_SCAN) bofs[t] = s[t] - v;
}

__global__ void k_scatterptr(const int* __restrict__ counts, const int* __restrict__ bofs,
                             int* __restrict__ row_ptr, int* __restrict__ cursor) {
    __shared__ int s[256];
    int t = threadIdx.x;
    int i = blockIdx.x * 256 + t;
    int v = (i < NN) ? counts[i] : 0;
    s[t] = v;
    __syncthreads();
    for (int off = 1; off < 256; off <<= 1) {
        int u = (t >= off) ? s[t - off] : 0;
        __syncthreads();
        s[t] += u;
        __syncthreads();
    }
    if (i < NN) {
        int ex = bofs[blockIdx.x] + s[t] - v;
        row_ptr[i] = ex;
        cursor[i] = ex;
    }
    if (i == NN - 1) row_ptr[NN] = NE;
}

__global__ void k_fill(const int* __restrict__ ei, const int* __restrict__ ea,
                       int* __restrict__ cursor, int* __restrict__ recs) {
    int e = blockIdx.x * blockDim.x + threadIdx.x;
    if (e >= NE) return;
    int src = ei[e];
    int dst = ei[NE + e];
    int a = ea[2 * e];
    int b = ea[2 * e + 1];
    int rec = src | ((a * 3 + b) << 20);
    int pos = atomicAdd(&cursor[dst], 1);
    recs[pos] = rec;
}

// transpose + f16 convert: W [L][K][N] fp32 -> T [L][N][K] f16
__global__ void k_wt(const float* __restrict__ W, _Float16* __restrict__ T, int K, int N) {
    __shared__ float t[32][33];
    int l = blockIdx.z;
    int k0 = blockIdx.y * 32, n0 = blockIdx.x * 32;
    int tx = threadIdx.x, ty = threadIdx.y;   // (32,8)
    const float* Wl = W + (size_t)l * K * N;
    _Float16* Tl = T + (size_t)l * N * K;
    for (int d = 0; d < 32; d += 8)
        t[ty + d][tx] = Wl[(size_t)(k0 + ty + d) * N + n0 + tx];
    __syncthreads();
    for (int d = 0; d < 32; d += 8)
        Tl[(size_t)(n0 + ty + d) * K + k0 + tx] = (_Float16)t[tx][ty + d];
}

// ---------------- aggregation: one wave per node (frozen — round-6 analysis:
// VALU-issue-bound at ~12 fp32 ops/edge/lane floor; Ctab in LDS; masked 4-wide
// ILP batches; f16 accumulate rejected on precision margin) ----------------
template <bool APPLY>
__global__ __launch_bounds__(256) void k_agg(const _Float16* __restrict__ rows,
                                             const float* __restrict__ ss,
                                             const float* __restrict__ Cl,
                                             const int* __restrict__ row_ptr,
                                             const int* __restrict__ recs,
                                             _Float16* __restrict__ aggh) {
    __shared__ __align__(16) float lC[9 * DIM];   // 9 KB edge-combo table
    {
        for (int i = threadIdx.x; i < 576; i += 256)
            ((float4*)lC)[i] = ((const float4*)Cl)[i];
    }
    int node = (blockIdx.x * blockDim.x + threadIdx.x) >> 6;
    int lane = threadIdx.x & 63;
    bool act = node < NN;
    int c = lane * 4;
    int e0 = 0, e1 = 0;
    float s0 = 1.f, s1 = 1.f, s2 = 1.f, s3 = 1.f, t0 = 0.f, t1 = 0.f, t2 = 0.f, t3 = 0.f;
    half4v sv = {0, 0, 0, 0};
    if (act) {
        e0 = row_ptr[node];
        e1 = row_ptr[node + 1];
        if (APPLY) {
            s0 = ss[c]; s1 = ss[c + 1]; s2 = ss[c + 2]; s3 = ss[c + 3];
            t0 = ss[DIM + c]; t1 = ss[DIM + c + 1]; t2 = ss[DIM + c + 2]; t3 = ss[DIM + c + 3];
        }
        sv = *(const half4v*)(rows + (size_t)node * DIM + c);
    }
    __syncthreads();
    if (!act) return;

    float4 cv0 = *(const float4*)(lC + c);   // self-loop attr = (0,0) -> combo 0
    float ax, ay, az, aw;
    if (APPLY) {
        ax = fmaxf((float)sv.x * s0 + t0, 0.f) + cv0.x;
        ay = fmaxf((float)sv.y * s1 + t1, 0.f) + cv0.y;
        az = fmaxf((float)sv.z * s2 + t2, 0.f) + cv0.z;
        aw = fmaxf((float)sv.w * s3 + t3, 0.f) + cv0.w;
    } else {
        ax = (float)sv.x + cv0.x;
        ay = (float)sv.y + cv0.y;
        az = (float)sv.z + cv0.z;
        aw = (float)sv.w + cv0.w;
    }

    int ec = e1 - 1;
    for (int e = e0; e < e1; e += 4) {
        int i1 = min(e + 1, ec), i2 = min(e + 2, ec), i3 = min(e + 3, ec);
        float v1 = (e + 1 <= ec) ? 1.f : 0.f;
        float v2 = (e + 2 <= ec) ? 1.f : 0.f;
        float v3 = (e + 3 <= ec) ? 1.f : 0.f;
        int r0 = recs[e], r1 = recs[i1], r2 = recs[i2], r3 = recs[i3];
        half4v h0 = *(const half4v*)(rows + (size_t)(r0 & 0xFFFFF) * DIM + c);
        half4v h1 = *(const half4v*)(rows + (size_t)(r1 & 0xFFFFF) * DIM + c);
        half4v h2 = *(const half4v*)(rows + (size_t)(r2 & 0xFFFFF) * DIM + c);
        half4v h3 = *(const half4v*)(rows + (size_t)(r3 & 0xFFFFF) * DIM + c);
        float4 c0 = *(const float4*)(lC + (r0 >> 20) * DIM + c);
        float4 c1 = *(const float4*)(lC + (r1 >> 20) * DIM + c);
        float4 c2 = *(const float4*)(lC + (r2 >> 20) * DIM + c);
        float4 c3 = *(const float4*)(lC + (r3 >> 20) * DIM + c);
        if (APPLY) {
            ax += fmaxf((float)h0.x * s0 + t0, 0.f) + c0.x;
            ay += fmaxf((float)h0.y * s1 + t1, 0.f) + c0.y;
            az += fmaxf((float)h0.z * s2 + t2, 0.f) + c0.z;
            aw += fmaxf((float)h0.w * s3 + t3, 0.f) + c0.w;
            ax = fmaf(v1, fmaxf((float)h1.x * s0 + t0, 0.f) + c1.x, ax);
            ay = fmaf(v1, fmaxf((float)h1.y * s1 + t1, 0.f) + c1.y, ay);
            az = fmaf(v1, fmaxf((float)h1.z * s2 + t2, 0.f) + c1.z, az);
            aw = fmaf(v1, fmaxf((float)h1.w * s3 + t3, 0.f) + c1.w, aw);
            ax = fmaf(v2, fmaxf((float)h2.x * s0 + t0, 0.f) + c2.x, ax);
            ay = fmaf(v2, fmaxf((float)h2.y * s1 + t1, 0.f) + c2.y, ay);
            az = fmaf(v2, fmaxf((float)h2.z * s2 + t2, 0.f) + c2.z, az);
            aw = fmaf(v2, fmaxf((float)h2.w * s3 + t3, 0.f) + c2.w, aw);
            ax = fmaf(v3, fmaxf((float)h3.x * s0 + t0, 0.f) + c3.x, ax);
            ay = fmaf(v3, fmaxf((float)h3.y * s1 + t1, 0.f) + c3.y, ay);
            az = fmaf(v3, fmaxf((float)h3.z * s2 + t2, 0.f) + c3.z, az);
            aw = fmaf(v3, fmaxf((float)h3.w * s3 + t3, 0.f) + c3.w, aw);
        } else {
            ax += (float)h0.x + c0.x;
            ay += (float)h0.y + c0.y;
            az += (float)h0.z + c0.z;
            aw += (float)h0.w + c0.w;
            ax = fmaf(v1, (float)h1.x + c1.x, ax);
            ay = fmaf(v1, (float)h1.y + c1.y, ay);
            az = fmaf(v1, (float)h1.z + c1.z, az);
            aw = fmaf(v1, (float)h1.w + c1.w, aw);
            ax = fmaf(v2, (float)h2.x + c2.x, ax);
            ay = fmaf(v2, (float)h2.y + c2.y, ay);
            az = fmaf(v2, (float)h2.z + c2.z, az);
            aw = fmaf(v2, (float)h2.w + c2.w, aw);
            ax = fmaf(v3, (float)h3.x + c3.x, ax);
            ay = fmaf(v3, (float)h3.y + c3.y, ay);
            az = fmaf(v3, (float)h3.z + c3.z, az);
            aw = fmaf(v3, (float)h3.w + c3.w, aw);
        }
    }
    half4v o;
    o.x = (_Float16)ax; o.y = (_Float16)ay; o.z = (_Float16)az; o.w = (_Float16)aw;
    *(half4v*)(aggh + (size_t)node * DIM + c) = o;
}

// ---------------- fused MLP: Z = (relu(A@W1+b1))@W2 + b2, + BN stats ----------------
// Round-7: SAME dataflow as the known-good round-0 kernel (64-row tile, A-chunk
// 16KB + H 64KB LDS, identical swizzles/barriers) but 8 WAVES of 512 threads:
// each wave owns half the old column slice (stage1 64 cols, acc1[4][4]=64 regs;
// stage2 32 cols, acc2[4][2]=32). __launch_bounds__(512,4) caps 128 regs/wave ->
// 2 blocks x 8 waves = 16 waves/CU (4/SIMD) vs 8: now 4 waves x ~77cy MFMA per
// qq-iter covers the ~250cy L2 latency of the W-operand loads. acc1/acc2 strictly
// sequential (rounds 1-4 spill mode absent); unroll 1 on qq/q bounds hoisting
// (stage-1 peak ~116 regs + 1-iter lookahead < 128).
__global__ __launch_bounds__(512, 4) void k_mlp(const _Float16* __restrict__ A,
                                                const _Float16* __restrict__ W1t,
                                                const float* __restrict__ b1,
                                                const _Float16* __restrict__ W2t,
                                                const float* __restrict__ b2,
                                                _Float16* __restrict__ Z,
                                                float* __restrict__ stats, int M) {
    __shared__ _Float16 ldsA[64 * 128];   // 16 KB (A k-chunk, swizzled)
    __shared__ _Float16 ldsH[64 * 512];   // 64 KB (H tile; reused as Z tile)
    int tid = threadIdx.x;
    int w = tid >> 6, lane = tid & 63;    // w: 0..7
    int lm = lane & 15, lg = lane >> 4;
    int row0 = blockIdx.x * 64;

    // ---------- stage 1 ----------
    float4v acc1[4][4];
    const float4v zero = {0.f, 0.f, 0.f, 0.f};
#pragma unroll
    for (int i = 0; i < 4; ++i)
#pragma unroll
        for (int j = 0; j < 4; ++j) acc1[i][j] = zero;

#pragma unroll
    for (int kc = 0; kc < 2; ++kc) {
        // stage A chunk: 64 rows x 128 k. Wave w stages rows w*8..w*8+7.
        {
            int srow = lane >> 4;      // 0..3
            int slot = lane & 15;      // 16B slot within 128-f16 row
#pragma unroll
            for (int j = 0; j < 2; ++j) {
                int cr = w * 8 + j * 4 + srow;
                int gr = min(row0 + cr, M - 1);
                int gk = kc * 128 + ((slot ^ (cr & 7)) * 8);
                gl_lds16(A + (size_t)gr * DIM + gk, ldsA + (w * 8 + j * 4) * 128);
            }
        }
        __syncthreads();
#pragma unroll 1
        for (int qq = 0; qq < 4; ++qq) {
            half8 bf[4];
#pragma unroll
            for (int nt = 0; nt < 4; ++nt) {
                int n = w * 64 + nt * 16 + lm;
                bf[nt] = *(const half8*)(W1t + (size_t)n * DIM + kc * 128 + qq * 32 + lg * 8);
            }
            half8 af[4];
#pragma unroll
            for (int mt = 0; mt < 4; ++mt) {
                int m = mt * 16 + lm;
                int slot = qq * 4 + lg;
                af[mt] = *(const half8*)(ldsA + m * 128 + ((slot ^ (m & 7)) * 8));
            }
#pragma unroll
            for (int mt = 0; mt < 4; ++mt)
#pragma unroll
                for (int nt = 0; nt < 4; ++nt)
                    acc1[mt][nt] = __builtin_amdgcn_mfma_f32_16x16x32_f16(af[mt], bf[nt],
                                                                          acc1[mt][nt], 0, 0, 0);
        }
        __syncthreads();
    }

    // H (relu) -> ldsH, f16, XOR-swizzled by row (C-layout: col=lm, row=lg*4+r)
#pragma unroll
    for (int nt = 0; nt < 4; ++nt) {
        int col = w * 64 + nt * 16 + lm;
        float bv = b1[col];
        int cs = col >> 3, ci = col & 7;
#pragma unroll
        for (int mt = 0; mt < 4; ++mt)
#pragma unroll
            for (int r = 0; r < 4; ++r) {
                int row = mt * 16 + lg * 4 + r;
                float v = fmaxf(acc1[mt][nt][r] + bv, 0.f);
                ldsH[row * 512 + ((cs ^ (row & 7)) << 3) + ci] = (_Float16)v;
            }
    }
    __syncthreads();

    // ---------- stage 2 ----------
    float4v acc2[4][2];
#pragma unroll
    for (int i = 0; i < 4; ++i)
#pragma unroll
        for (int j = 0; j < 2; ++j) acc2[i][j] = zero;

#pragma unroll 1
    for (int q = 0; q < 16; ++q) {
        half8 bf[2];
#pragma unroll
        for (int nt = 0; nt < 2; ++nt) {
            int n = w * 32 + nt * 16 + lm;
            bf[nt] = *(const half8*)(W2t + (size_t)n * HID + q * 32 + lg * 8);
        }
        half8 af[4];
#pragma unroll
        for (int mt = 0; mt < 4; ++mt) {
            int m = mt * 16 + lm;
            int slot = q * 4 + lg;                 // 0..63
            af[mt] = *(const half8*)(ldsH + m * 512 + ((slot ^ (m & 7)) << 3));
        }
#pragma unroll
        for (int mt = 0; mt < 4; ++mt)
#pragma unroll
            for (int nt = 0; nt < 2; ++nt)
                acc2[mt][nt] = __builtin_amdgcn_mfma_f32_16x16x32_f16(af[mt], bf[nt],
                                                                      acc2[mt][nt], 0, 0, 0);
    }
    __syncthreads();   // ldsH free -> reuse as Z tile

    // ---------- epilogue: bias + stats + z via LDS transpose ----------
    _Float16* ldsZ = ldsH;   // 64 x 256 f16, swizzled
    float psum[2], psq[2];
#pragma unroll
    for (int nt = 0; nt < 2; ++nt) { psum[nt] = 0.f; psq[nt] = 0.f; }
#pragma unroll
    for (int nt = 0; nt < 2; ++nt) {
        int col = w * 32 + nt * 16 + lm;
        float bv = b2[col];
        int cs = col >> 3, ci = col & 7;
#pragma unroll
        for (int mt = 0; mt < 4; ++mt)
#pragma unroll
            for (int r = 0; r < 4; ++r) {
                int row = mt * 16 + lg * 4 + r;
                float v = acc2[mt][nt][r] + bv;
                if (row0 + row < M) {
                    psum[nt] += v;
                    psq[nt] += v * v;
                }
                ldsZ[row * 256 + ((cs ^ (row & 7)) << 3) + ci] = (_Float16)v;
            }
    }
#pragma unroll
    for (int nt = 0; nt < 2; ++nt) {
        psum[nt] += __shfl_xor(psum[nt], 16);
        psum[nt] += __shfl_xor(psum[nt], 32);
        psq[nt] += __shfl_xor(psq[nt], 16);
        psq[nt] += __shfl_xor(psq[nt], 32);
    }
    if (lg == 0) {
#pragma unroll
        for (int nt = 0; nt < 2; ++nt) {
            int ch = w * 32 + nt * 16 + lm;
            atomicAdd(&stats[ch], psum[nt]);
            atomicAdd(&stats[DIM + ch], psq[nt]);
        }
    }
    __syncthreads();
    // coalesced store: 2048 16B-slots, thread t -> slots t, t+512, ...
#pragma unroll
    for (int i = 0; i < 4; ++i) {
        int s = i * 512 + tid;
        int row = s >> 5, c16 = s & 31;
        if (row0 + row < M) {
            half8 v = *(const half8*)(ldsZ + row * 256 + ((c16 ^ (row & 7)) << 3));
            *(half8*)(Z + (size_t)(row0 + row) * DIM + c16 * 8) = v;
        }
    }
}

// ---------------- BatchNorm finalize (also re-zeros stats) + final output ----------------
__global__ void k_bnfin(float* __restrict__ stats, const float* __restrict__ gamma,
                        const float* __restrict__ beta, float* __restrict__ ss) {
    int c = threadIdx.x;
    float mu = stats[c] * (1.0f / NN);
    float var = stats[DIM + c] * (1.0f / NN) - mu * mu;
    float sc = gamma[c] / sqrtf(var + BN_EPS);
    ss[c] = sc;
    ss[DIM + c] = beta[c] - mu * sc;
    stats[c] = 0.f;
    stats[DIM + c] = 0.f;
}

__global__ void k_out(const _Float16* __restrict__ z, const float* __restrict__ ss,
                      float* __restrict__ out) {
    int i = blockIdx.x * blockDim.x + threadIdx.x;
    if (i >= NN * DIM / 4) return;
    int c4 = (i & (DIM / 4 - 1)) * 4;
    half4v v = ((const half4v*)z)[i];
    float4 o;
    o.x = (float)v.x * ss[c4] + ss[DIM + c4];
    o.y = (float)v.y * ss[c4 + 1] + ss[DIM + c4 + 1];
    o.z = (float)v.z * ss[c4 + 2] + ss[DIM + c4 + 2];
    o.w = (float)v.w * ss[c4 + 3] + ss[DIM + c4 + 3];
    ((float4*)out)[i] = o;
}

// ---------------- host launcher ----------------
extern "C" void kernel_launch(void* const* d_in, const int* in_sizes, int n_in,
                              void* d_out, int out_size, void* d_ws, size_t ws_size,
                              hipStream_t stream) {
    const float* x = (const float*)d_in[0];
    const int* ei = (const int*)d_in[1];
    const int* ea = (const int*)d_in[2];
    const float* W1 = (const float*)d_in[4];
    const float* b1 = (const float*)d_in[5];
    const float* W2 = (const float*)d_in[6];
    const float* b2 = (const float*)d_in[7];
    const float* E1 = (const float*)d_in[8];
    const float* E2 = (const float*)d_in[9];
    const float* gamma = (const float*)d_in[10];
    const float* beta = (const float*)d_in[11];
    float* out = (float*)d_out;

    char* w = (char*)d_ws;
    _Float16* xh = (_Float16*)w;   w += (size_t)NN * DIM * 2;
    _Float16* z = (_Float16*)w;    w += (size_t)NN * DIM * 2;
    _Float16* aggh = (_Float16*)w; w += (size_t)NN * DIM * 2;
    _Float16* W1t = (_Float16*)w;  w += (size_t)NL * DIM * HID * 2;
    _Float16* W2t = (_Float16*)w;  w += (size_t)NL * HID * DIM * 2;
    float* Ctab = (float*)w;       w += (size_t)NL * 9 * DIM * 4;
    float* stats = (float*)w;      w += 2 * DIM * 4;
    float* ss = (float*)w;         w += 2 * DIM * 4;
    int* row_ptr = (int*)w;        w += (size_t)(NN + 2) * 4;
    int* counts = (int*)w;         w += (size_t)NN * 4;
    int* cursor = (int*)w;         w += (size_t)NN * 4;
    int* bsum = (int*)w;           w += 256 * 4;
    int* bofs = (int*)w;           w += 256 * 4;
    int* recs = (int*)w;           w += (size_t)NE * 4;

    // setup: f16 x, edge-combo tables, CSR by dst, transposed f16 weights
    k_zero<<<(NN + 255) / 256, 256, 0, stream>>>(counts, NN);
    k_zero<<<2, 256, 0, stream>>>((int*)stats, 2 * DIM);
    k_x2h<<<(NN * DIM / 4 + 255) / 256, 256, 0, stream>>>(x, xh);
    k_ctab<<<NL * 9, 256, 0, stream>>>(E1, E2, Ctab);
    k_hist<<<(NE + 255) / 256, 256, 0, stream>>>(ei, counts);
    k_bsum<<<NB_SCAN, 256, 0, stream>>>(counts, bsum);
    k_bscan<<<1, 256, 0, stream>>>(bsum, bofs);
    k_scatterptr<<<NB_SCAN, 256, 0, stream>>>(counts, bofs, row_ptr, cursor);
    k_fill<<<(NE + 255) / 256, 256, 0, stream>>>(ei, ea, cursor, recs);
    {
        dim3 b(32, 8);
        dim3 g1(HID / 32, DIM / 32, NL);
        k_wt<<<g1, b, 0, stream>>>(W1, W1t, DIM, HID);
        dim3 g2(DIM / 32, HID / 32, NL);
        k_wt<<<g2, b, 0, stream>>>(W2, W2t, HID, DIM);
    }

    for (int l = 0; l < NL; ++l) {
        const float* Cl = Ctab + (size_t)l * 9 * DIM;
        if (l == 0)
            k_agg<false><<<(NN + 3) / 4, 256, 0, stream>>>(xh, ss, Cl, row_ptr, recs, aggh);
        else
            k_agg<true><<<(NN + 3) / 4, 256, 0, stream>>>(z, ss, Cl, row_ptr, recs, aggh);

        k_mlp<<<(NN + 63) / 64, 512, 0, stream>>>(aggh, W1t + (size_t)l * DIM * HID,
                                                  b1 + (size_t)l * HID,
                                                  W2t + (size_t)l * HID * DIM,
                                                  b2 + (size_t)l * DIM, z, stats, NN);

        k_bnfin<<<1, 256, 0, stream>>>(stats, gamma + (size_t)l * DIM, beta + (size_t)l * DIM, ss);
    }
    k_out<<<(NN * DIM / 4 + 255) / 256, 256, 0, stream>>>(z, ss, out);
}

// Round 8
// 749.368 us; speedup vs baseline: 1.0437x; 1.0437x over previous
//
#include <hip/hip_runtime.h>

#define NN 50000
#define NE 400000
#define DIM 256
#define HID 512
#define NL 5
#define BN_EPS 1e-5f
#define NB_SCAN 196   // ceil(NN/256)

typedef float float4v __attribute__((ext_vector_type(4)));
typedef _Float16 half8 __attribute__((ext_vector_type(8)));
typedef _Float16 half4v __attribute__((ext_vector_type(4)));

__device__ __forceinline__ void gl_lds16(const void* g, void* l) {
    __builtin_amdgcn_global_load_lds((__attribute__((address_space(1))) void*)g,
                                     (__attribute__((address_space(3))) void*)l, 16, 0, 0);
}

// ---------------- setup kernels ----------------

__global__ void k_zero(int* p, int n) {
    int i = blockIdx.x * blockDim.x + threadIdx.x;
    if (i < n) p[i] = 0;
}

__global__ void k_x2h(const float* __restrict__ x, _Float16* __restrict__ xh) {
    int i = blockIdx.x * blockDim.x + threadIdx.x;
    if (i >= NN * DIM / 4) return;
    float4 v = ((const float4*)x)[i];
    half4v o;
    o.x = (_Float16)v.x; o.y = (_Float16)v.y; o.z = (_Float16)v.z; o.w = (_Float16)v.w;
    ((half4v*)xh)[i] = o;
}

// C[l][a*3+b][c] = E1[l][a][c] + E2[l][b][c]
__global__ void k_ctab(const float* __restrict__ E1, const float* __restrict__ E2,
                       float* __restrict__ C) {
    int b = blockIdx.x;            // 0..44
    int l = b / 9, ab = b % 9;
    int a = ab / 3, bb = ab % 3;
    int c = threadIdx.x;
    C[(size_t)b * DIM + c] = E1[(size_t)(l * 6 + a) * DIM + c] + E2[(size_t)(l * 3 + bb) * DIM + c];
}

__global__ void k_hist(const int* __restrict__ ei, int* __restrict__ counts) {
    int e = blockIdx.x * blockDim.x + threadIdx.x;
    if (e < NE) atomicAdd(&counts[ei[NE + e]], 1);
}

// ---- multi-block coalesced exclusive scan of counts -> row_ptr/cursor ----
__global__ void k_bsum(const int* __restrict__ counts, int* __restrict__ bsum) {
    __shared__ int s[256];
    int t = threadIdx.x;
    int i = blockIdx.x * 256 + t;
    s[t] = (i < NN) ? counts[i] : 0;
    __syncthreads();
    for (int off = 128; off > 0; off >>= 1) {
        if (t < off) s[t] += s[t + off];
        __syncthreads();
    }
    if (t == 0) bsum[blockIdx.x] = s[0];
}

__global__ void k_bscan(const int* __restrict__ bsum, int* __restrict__ bofs) {
    __shared__ int s[256];
    int t = threadIdx.x;
    int v = (t < NB_SCAN) ? bsum[t] : 0;
    s[t] = v;
    __syncthreads();
    for (int off = 1; off < 256; off <<= 1) {
        int u = (t >= off) ? s[t - off] : 0;
        __syncthreads();
        s[t] += u;
        __syncthreads();
    }
    if (t < NB_SCAN) bofs[t] = s[t] - v;
}

__global__ void k_scatterptr(const int* __restrict__ counts, const int* __restrict__ bofs,
                             int* __restrict__ row_ptr, int* __restrict__ cursor) {
    __shared__ int s[256];
    int t = threadIdx.x;
    int i = blockIdx.x * 256 + t;
    int v = (i < NN) ? counts[i] : 0;
    s[t] = v;
    __syncthreads();
    for (int off = 1; off < 256; off <<= 1) {
        int u = (t >= off) ? s[t - off] : 0;
        __syncthreads();
        s[t] += u;
        __syncthreads();
    }
    if (i < NN) {
        int ex = bofs[blockIdx.x] + s[t] - v;
        row_ptr[i] = ex;
        cursor[i] = ex;
    }
    if (i == NN - 1) row_ptr[NN] = NE;
}

__global__ void k_fill(const int* __restrict__ ei, const int* __restrict__ ea,
                       int* __restrict__ cursor, int* __restrict__ recs) {
    int e = blockIdx.x * blockDim.x + threadIdx.x;
    if (e >= NE) return;
    int src = ei[e];
    int dst = ei[NE + e];
    int a = ea[2 * e];
    int b = ea[2 * e + 1];
    int rec = src | ((a * 3 + b) << 20);
    int pos = atomicAdd(&cursor[dst], 1);
    recs[pos] = rec;
}

// transpose + f16 convert: W [L][K][N] fp32 -> T [L][N][K] f16
__global__ void k_wt(const float* __restrict__ W, _Float16* __restrict__ T, int K, int N) {
    __shared__ float t[32][33];
    int l = blockIdx.z;
    int k0 = blockIdx.y * 32, n0 = blockIdx.x * 32;
    int tx = threadIdx.x, ty = threadIdx.y;   // (32,8)
    const float* Wl = W + (size_t)l * K * N;
    _Float16* Tl = T + (size_t)l * N * K;
    for (int d = 0; d < 32; d += 8)
        t[ty + d][tx] = Wl[(size_t)(k0 + ty + d) * N + n0 + tx];
    __syncthreads();
    for (int d = 0; d < 32; d += 8)
        Tl[(size_t)(n0 + ty + d) * K + k0 + tx] = (_Float16)t[tx][ty + d];
}

// ---------------- aggregation: one wave per node (frozen — round-6 analysis:
// VALU-issue-bound at ~12 fp32 ops/edge/lane floor; Ctab in LDS; masked 4-wide
// ILP batches; f16 accumulate rejected on precision margin) ----------------
template <bool APPLY>
__global__ __launch_bounds__(256) void k_agg(const _Float16* __restrict__ rows,
                                             const float* __restrict__ ss,
                                             const float* __restrict__ Cl,
                                             const int* __restrict__ row_ptr,
                                             const int* __restrict__ recs,
                                             _Float16* __restrict__ aggh) {
    __shared__ __align__(16) float lC[9 * DIM];   // 9 KB edge-combo table
    {
        for (int i = threadIdx.x; i < 576; i += 256)
            ((float4*)lC)[i] = ((const float4*)Cl)[i];
    }
    int node = (blockIdx.x * blockDim.x + threadIdx.x) >> 6;
    int lane = threadIdx.x & 63;
    bool act = node < NN;
    int c = lane * 4;
    int e0 = 0, e1 = 0;
    float s0 = 1.f, s1 = 1.f, s2 = 1.f, s3 = 1.f, t0 = 0.f, t1 = 0.f, t2 = 0.f, t3 = 0.f;
    half4v sv = {0, 0, 0, 0};
    if (act) {
        e0 = row_ptr[node];
        e1 = row_ptr[node + 1];
        if (APPLY) {
            s0 = ss[c]; s1 = ss[c + 1]; s2 = ss[c + 2]; s3 = ss[c + 3];
            t0 = ss[DIM + c]; t1 = ss[DIM + c + 1]; t2 = ss[DIM + c + 2]; t3 = ss[DIM + c + 3];
        }
        sv = *(const half4v*)(rows + (size_t)node * DIM + c);
    }
    __syncthreads();
    if (!act) return;

    float4 cv0 = *(const float4*)(lC + c);   // self-loop attr = (0,0) -> combo 0
    float ax, ay, az, aw;
    if (APPLY) {
        ax = fmaxf((float)sv.x * s0 + t0, 0.f) + cv0.x;
        ay = fmaxf((float)sv.y * s1 + t1, 0.f) + cv0.y;
        az = fmaxf((float)sv.z * s2 + t2, 0.f) + cv0.z;
        aw = fmaxf((float)sv.w * s3 + t3, 0.f) + cv0.w;
    } else {
        ax = (float)sv.x + cv0.x;
        ay = (float)sv.y + cv0.y;
        az = (float)sv.z + cv0.z;
        aw = (float)sv.w + cv0.w;
    }

    int ec = e1 - 1;
    for (int e = e0; e < e1; e += 4) {
        int i1 = min(e + 1, ec), i2 = min(e + 2, ec), i3 = min(e + 3, ec);
        float v1 = (e + 1 <= ec) ? 1.f : 0.f;
        float v2 = (e + 2 <= ec) ? 1.f : 0.f;
        float v3 = (e + 3 <= ec) ? 1.f : 0.f;
        int r0 = recs[e], r1 = recs[i1], r2 = recs[i2], r3 = recs[i3];
        half4v h0 = *(const half4v*)(rows + (size_t)(r0 & 0xFFFFF) * DIM + c);
        half4v h1 = *(const half4v*)(rows + (size_t)(r1 & 0xFFFFF) * DIM + c);
        half4v h2 = *(const half4v*)(rows + (size_t)(r2 & 0xFFFFF) * DIM + c);
        half4v h3 = *(const half4v*)(rows + (size_t)(r3 & 0xFFFFF) * DIM + c);
        float4 c0 = *(const float4*)(lC + (r0 >> 20) * DIM + c);
        float4 c1 = *(const float4*)(lC + (r1 >> 20) * DIM + c);
        float4 c2 = *(const float4*)(lC + (r2 >> 20) * DIM + c);
        float4 c3 = *(const float4*)(lC + (r3 >> 20) * DIM + c);
        if (APPLY) {
            ax += fmaxf((float)h0.x * s0 + t0, 0.f) + c0.x;
            ay += fmaxf((float)h0.y * s1 + t1, 0.f) + c0.y;
            az += fmaxf((float)h0.z * s2 + t2, 0.f) + c0.z;
            aw += fmaxf((float)h0.w * s3 + t3, 0.f) + c0.w;
            ax = fmaf(v1, fmaxf((float)h1.x * s0 + t0, 0.f) + c1.x, ax);
            ay = fmaf(v1, fmaxf((float)h1.y * s1 + t1, 0.f) + c1.y, ay);
            az = fmaf(v1, fmaxf((float)h1.z * s2 + t2, 0.f) + c1.z, az);
            aw = fmaf(v1, fmaxf((float)h1.w * s3 + t3, 0.f) + c1.w, aw);
            ax = fmaf(v2, fmaxf((float)h2.x * s0 + t0, 0.f) + c2.x, ax);
            ay = fmaf(v2, fmaxf((float)h2.y * s1 + t1, 0.f) + c2.y, ay);
            az = fmaf(v2, fmaxf((float)h2.z * s2 + t2, 0.f) + c2.z, az);
            aw = fmaf(v2, fmaxf((float)h2.w * s3 + t3, 0.f) + c2.w, aw);
            ax = fmaf(v3, fmaxf((float)h3.x * s0 + t0, 0.f) + c3.x, ax);
            ay = fmaf(v3, fmaxf((float)h3.y * s1 + t1, 0.f) + c3.y, ay);
            az = fmaf(v3, fmaxf((float)h3.z * s2 + t2, 0.f) + c3.z, az);
            aw = fmaf(v3, fmaxf((float)h3.w * s3 + t3, 0.f) + c3.w, aw);
        } else {
            ax += (float)h0.x + c0.x;
            ay += (float)h0.y + c0.y;
            az += (float)h0.z + c0.z;
            aw += (float)h0.w + c0.w;
            ax = fmaf(v1, (float)h1.x + c1.x, ax);
            ay = fmaf(v1, (float)h1.y + c1.y, ay);
            az = fmaf(v1, (float)h1.z + c1.z, az);
            aw = fmaf(v1, (float)h1.w + c1.w, aw);
            ax = fmaf(v2, (float)h2.x + c2.x, ax);
            ay = fmaf(v2, (float)h2.y + c2.y, ay);
            az = fmaf(v2, (float)h2.z + c2.z, az);
            aw = fmaf(v2, (float)h2.w + c2.w, aw);
            ax = fmaf(v3, (float)h3.x + c3.x, ax);
            ay = fmaf(v3, (float)h3.y + c3.y, ay);
            az = fmaf(v3, (float)h3.z + c3.z, az);
            aw = fmaf(v3, (float)h3.w + c3.w, aw);
        }
    }
    half4v o;
    o.x = (_Float16)ax; o.y = (_Float16)ay; o.z = (_Float16)az; o.w = (_Float16)aw;
    *(half4v*)(aggh + (size_t)node * DIM + c) = o;
}

// ---------------- fused MLP: Z = (relu(A@W1+b1))@W2 + b2, + BN stats ----------------
// Round-8: same 8-wave/512-thread decomposition as round-7 (known-correct, no
// spill, 2 blocks/CU) + IN-WAVE MLP on the W loads. Round-7 falsified the
// occupancy theory (8->16 waves/CU, dur unchanged 85us): the bound is the
// per-wave serial chain of 24 dependent W-load waits. Stage-2 (16 of 24) now
// runs a depth-4 prefetch ring p0..p3 (+32 VGPR): 4 prologue loads issued
// BEFORE the H-barrier (its vmcnt(0) drain pays one latency for 4 loads);
// in-loop reloads are 4 steps (~600cy LDS+MFMA) ahead of use. Straight-line
// 16 steps (no unroll-1 loop) so the scheduler may hoist af reads. Stage-1
// keeps a single bf buffer (depth-2 would hit ~132 regs > the 128 cap of
// (512,4) -> spill, the rounds-1-4 failure mode); only its qq=0 load moves
// before the staging barrier (free batching under the drain).
// Register audit: stage1 acc1(64)+bf(16)+af(16)+addr ~= 110; stage2
// acc2(32)+p(32)+af(16)+addr ~= 95. Both < 128.
__global__ __launch_bounds__(512, 4) void k_mlp(const _Float16* __restrict__ A,
                                                const _Float16* __restrict__ W1t,
                                                const float* __restrict__ b1,
                                                const _Float16* __restrict__ W2t,
                                                const float* __restrict__ b2,
                                                _Float16* __restrict__ Z,
                                                float* __restrict__ stats, int M) {
    __shared__ _Float16 ldsA[64 * 128];   // 16 KB (A k-chunk, swizzled)
    __shared__ _Float16 ldsH[64 * 512];   // 64 KB (H tile; reused as Z tile)
    int tid = threadIdx.x;
    int w = tid >> 6, lane = tid & 63;    // w: 0..7
    int lm = lane & 15, lg = lane >> 4;
    int row0 = blockIdx.x * 64;

    // ---------- stage 1 ----------
    const float4v zero = {0.f, 0.f, 0.f, 0.f};
    float4v acc1[4][4];
#pragma unroll
    for (int i = 0; i < 4; ++i)
#pragma unroll
        for (int j = 0; j < 4; ++j) acc1[i][j] = zero;

    auto s1_load = [&](half8 (&pb)[4], int kc, int qq) {
#pragma unroll
        for (int nt = 0; nt < 4; ++nt) {
            int n = w * 64 + nt * 16 + lm;
            pb[nt] = *(const half8*)(W1t + (size_t)n * DIM + kc * 128 + qq * 32 + lg * 8);
        }
    };
    auto s1_step = [&](half8 (&pb)[4], int qq) {
        half8 af[4];
#pragma unroll
        for (int mt = 0; mt < 4; ++mt) {
            int m = mt * 16 + lm;
            int slot = qq * 4 + lg;
            af[mt] = *(const half8*)(ldsA + m * 128 + ((slot ^ (m & 7)) * 8));
        }
#pragma unroll
        for (int mt = 0; mt < 4; ++mt)
#pragma unroll
            for (int nt = 0; nt < 4; ++nt)
                acc1[mt][nt] = __builtin_amdgcn_mfma_f32_16x16x32_f16(af[mt], pb[nt],
                                                                      acc1[mt][nt], 0, 0, 0);
    };

    half8 bf[4];
#pragma unroll
    for (int kc = 0; kc < 2; ++kc) {
        // stage A chunk: 64 rows x 128 k. Wave w stages rows w*8..w*8+7.
        {
            int srow = lane >> 4;      // 0..3
            int slot = lane & 15;      // 16B slot within 128-f16 row
#pragma unroll
            for (int j = 0; j < 2; ++j) {
                int cr = w * 8 + j * 4 + srow;
                int gr = min(row0 + cr, M - 1);
                int gk = kc * 128 + ((slot ^ (cr & 7)) * 8);
                gl_lds16(A + (size_t)gr * DIM + gk, ldsA + (w * 8 + j * 4) * 128);
            }
        }
        s1_load(bf, kc, 0);   // in flight across the barrier's vmcnt(0) drain
        __syncthreads();
        s1_step(bf, 0);
        s1_load(bf, kc, 1);
        s1_step(bf, 1);
        s1_load(bf, kc, 2);
        s1_step(bf, 2);
        s1_load(bf, kc, 3);
        s1_step(bf, 3);
        __syncthreads();
    }

    // H (relu) -> ldsH, f16, XOR-swizzled by row (C-layout: col=lm, row=lg*4+r)
#pragma unroll
    for (int nt = 0; nt < 4; ++nt) {
        int col = w * 64 + nt * 16 + lm;
        float bv = b1[col];
        int cs = col >> 3, ci = col & 7;
#pragma unroll
        for (int mt = 0; mt < 4; ++mt)
#pragma unroll
            for (int r = 0; r < 4; ++r) {
                int row = mt * 16 + lg * 4 + r;
                float v = fmaxf(acc1[mt][nt][r] + bv, 0.f);
                ldsH[row * 512 + ((cs ^ (row & 7)) << 3) + ci] = (_Float16)v;
            }
    }

    // ---------- stage 2 (depth-4 software-pipelined W2t loads) ----------
    float4v acc2[4][2];
#pragma unroll
    for (int i = 0; i < 4; ++i)
#pragma unroll
        for (int j = 0; j < 2; ++j) acc2[i][j] = zero;

    auto s2_load = [&](half8 (&pb)[2], int q) {
#pragma unroll
        for (int nt = 0; nt < 2; ++nt) {
            int n = w * 32 + nt * 16 + lm;
            pb[nt] = *(const half8*)(W2t + (size_t)n * HID + q * 32 + lg * 8);
        }
    };
    auto s2_step = [&](half8 (&pb)[2], int q) {
        half8 af[4];
#pragma unroll
        for (int mt = 0; mt < 4; ++mt) {
            int m = mt * 16 + lm;
            int slot = q * 4 + lg;                 // 0..63
            af[mt] = *(const half8*)(ldsH + m * 512 + ((slot ^ (m & 7)) << 3));
        }
#pragma unroll
        for (int mt = 0; mt < 4; ++mt)
#pragma unroll
            for (int nt = 0; nt < 2; ++nt)
                acc2[mt][nt] = __builtin_amdgcn_mfma_f32_16x16x32_f16(af[mt], pb[nt],
                                                                      acc2[mt][nt], 0, 0, 0);
    };

    half8 p0[2], p1[2], p2[2], p3[2];
    // prologue: 4 loads in flight across the barrier drain (global only, no LDS dep)
    s2_load(p0, 0); s2_load(p1, 1); s2_load(p2, 2); s2_load(p3, 3);
    __syncthreads();   // H visible
    s2_step(p0, 0);  s2_load(p0, 4);
    s2_step(p1, 1);  s2_load(p1, 5);
    s2_step(p2, 2);  s2_load(p2, 6);
    s2_step(p3, 3);  s2_load(p3, 7);
    s2_step(p0, 4);  s2_load(p0, 8);
    s2_step(p1, 5);  s2_load(p1, 9);
    s2_step(p2, 6);  s2_load(p2, 10);
    s2_step(p3, 7);  s2_load(p3, 11);
    s2_step(p0, 8);  s2_load(p0, 12);
    s2_step(p1, 9);  s2_load(p1, 13);
    s2_step(p2, 10); s2_load(p2, 14);
    s2_step(p3, 11); s2_load(p3, 15);
    s2_step(p0, 12);
    s2_step(p1, 13);
    s2_step(p2, 14);
    s2_step(p3, 15);
    __syncthreads();   // ldsH free -> reuse as Z tile

    // ---------- epilogue: bias + stats + z via LDS transpose ----------
    _Float16* ldsZ = ldsH;   // 64 x 256 f16, swizzled
    float psum[2], psq[2];
#pragma unroll
    for (int nt = 0; nt < 2; ++nt) { psum[nt] = 0.f; psq[nt] = 0.f; }
#pragma unroll
    for (int nt = 0; nt < 2; ++nt) {
        int col = w * 32 + nt * 16 + lm;
        float bv = b2[col];
        int cs = col >> 3, ci = col & 7;
#pragma unroll
        for (int mt = 0; mt < 4; ++mt)
#pragma unroll
            for (int r = 0; r < 4; ++r) {
                int row = mt * 16 + lg * 4 + r;
                float v = acc2[mt][nt][r] + bv;
                if (row0 + row < M) {
                    psum[nt] += v;
                    psq[nt] += v * v;
                }
                ldsZ[row * 256 + ((cs ^ (row & 7)) << 3) + ci] = (_Float16)v;
            }
    }
#pragma unroll
    for (int nt = 0; nt < 2; ++nt) {
        psum[nt] += __shfl_xor(psum[nt], 16);
        psum[nt] += __shfl_xor(psum[nt], 32);
        psq[nt] += __shfl_xor(psq[nt], 16);
        psq[nt] += __shfl_xor(psq[nt], 32);
    }
    if (lg == 0) {
#pragma unroll
        for (int nt = 0; nt < 2; ++nt) {
            int ch = w * 32 + nt * 16 + lm;
            atomicAdd(&stats[ch], psum[nt]);
            atomicAdd(&stats[DIM + ch], psq[nt]);
        }
    }
    __syncthreads();
    // coalesced store: 2048 16B-slots, thread t -> slots t, t+512, ...
#pragma unroll
    for (int i = 0; i < 4; ++i) {
        int s = i * 512 + tid;
        int row = s >> 5, c16 = s & 31;
        if (row0 + row < M) {
            half8 v = *(const half8*)(ldsZ + row * 256 + ((c16 ^ (row & 7)) << 3));
            *(half8*)(Z + (size_t)(row0 + row) * DIM + c16 * 8) = v;
        }
    }
}

// ---------------- BatchNorm finalize (also re-zeros stats) + final output ----------------
__global__ void k_bnfin(float* __restrict__ stats, const float* __restrict__ gamma,
                        const float* __restrict__ beta, float* __restrict__ ss) {
    int c = threadIdx.x;
    float mu = stats[c] * (1.0f / NN);
    float var = stats[DIM + c] * (1.0f / NN) - mu * mu;
    float sc = gamma[c] / sqrtf(var + BN_EPS);
    ss[c] = sc;
    ss[DIM + c] = beta[c] - mu * sc;
    stats[c] = 0.f;
    stats[DIM + c] = 0.f;
}

__global__ void k_out(const _Float16* __restrict__ z, const float* __restrict__ ss,
                      float* __restrict__ out) {
    int i = blockIdx.x * blockDim.x + threadIdx.x;
    if (i >= NN * DIM / 4) return;
    int c4 = (i & (DIM / 4 - 1)) * 4;
    half4v v = ((const half4v*)z)[i];
    float4 o;
    o.x = (float)v.x * ss[c4] + ss[DIM + c4];
    o.y = (float)v.y * ss[c4 + 1] + ss[DIM + c4 + 1];
    o.z = (float)v.z * ss[c4 + 2] + ss[DIM + c4 + 2];
    o.w = (float)v.w * ss[c4 + 3] + ss[DIM + c4 + 3];
    ((float4*)out)[i] = o;
}

// ---------------- host launcher ----------------
extern "C" void kernel_launch(void* const* d_in, const int* in_sizes, int n_in,
                              void* d_out, int out_size, void* d_ws, size_t ws_size,
                              hipStream_t stream) {
    const float* x = (const float*)d_in[0];
    const int* ei = (const int*)d_in[1];
    const int* ea = (const int*)d_in[2];
    const float* W1 = (const float*)d_in[4];
    const float* b1 = (const float*)d_in[5];
    const float* W2 = (const float*)d_in[6];
    const float* b2 = (const float*)d_in[7];
    const float* E1 = (const float*)d_in[8];
    const float* E2 = (const float*)d_in[9];
    const float* gamma = (const float*)d_in[10];
    const float* beta = (const float*)d_in[11];
    float* out = (float*)d_out;

    char* w = (char*)d_ws;
    _Float16* xh = (_Float16*)w;   w += (size_t)NN * DIM * 2;
    _Float16* z = (_Float16*)w;    w += (size_t)NN * DIM * 2;
    _Float16* aggh = (_Float16*)w; w += (size_t)NN * DIM * 2;
    _Float16* W1t = (_Float16*)w;  w += (size_t)NL * DIM * HID * 2;
    _Float16* W2t = (_Float16*)w;  w += (size_t)NL * HID * DIM * 2;
    float* Ctab = (float*)w;       w += (size_t)NL * 9 * DIM * 4;
    float* stats = (float*)w;      w += 2 * DIM * 4;
    float* ss = (float*)w;         w += 2 * DIM * 4;
    int* row_ptr = (int*)w;        w += (size_t)(NN + 2) * 4;
    int* counts = (int*)w;         w += (size_t)NN * 4;
    int* cursor = (int*)w;         w += (size_t)NN * 4;
    int* bsum = (int*)w;           w += 256 * 4;
    int* bofs = (int*)w;           w += 256 * 4;
    int* recs = (int*)w;           w += (size_t)NE * 4;

    // setup: f16 x, edge-combo tables, CSR by dst, transposed f16 weights
    k_zero<<<(NN + 255) / 256, 256, 0, stream>>>(counts, NN);
    k_zero<<<2, 256, 0, stream>>>((int*)stats, 2 * DIM);
    k_x2h<<<(NN * DIM / 4 + 255) / 256, 256, 0, stream>>>(x, xh);
    k_ctab<<<NL * 9, 256, 0, stream>>>(E1, E2, Ctab);
    k_hist<<<(NE + 255) / 256, 256, 0, stream>>>(ei, counts);
    k_bsum<<<NB_SCAN, 256, 0, stream>>>(counts, bsum);
    k_bscan<<<1, 256, 0, stream>>>(bsum, bofs);
    k_scatterptr<<<NB_SCAN, 256, 0, stream>>>(counts, bofs, row_ptr, cursor);
    k_fill<<<(NE + 255) / 256, 256, 0, stream>>>(ei, ea, cursor, recs);
    {
        dim3 b(32, 8);
        dim3 g1(HID / 32, DIM / 32, NL);
        k_wt<<<g1, b, 0, stream>>>(W1, W1t, DIM, HID);
        dim3 g2(DIM / 32, HID / 32, NL);
        k_wt<<<g2, b, 0, stream>>>(W2, W2t, HID, DIM);
    }

    for (int l = 0; l < NL; ++l) {
        const float* Cl = Ctab + (size_t)l * 9 * DIM;
        if (l == 0)
            k_agg<false><<<(NN + 3) / 4, 256, 0, stream>>>(xh, ss, Cl, row_ptr, recs, aggh);
        else
            k_agg<true><<<(NN + 3) / 4, 256, 0, stream>>>(z, ss, Cl, row_ptr, recs, aggh);

        k_mlp<<<(NN + 63) / 64, 512, 0, stream>>>(aggh, W1t + (size_t)l * DIM * HID,
                                                  b1 + (size_t)l * HID,
                                                  W2t + (size_t)l * HID * DIM,
                                                  b2 + (size_t)l * DIM, z, stats, NN);

        k_bnfin<<<1, 256, 0, stream>>>(stats, gamma + (size_t)l * DIM, beta + (size_t)l * DIM, ss);
    }
    k_out<<<(NN * DIM / 4 + 255) / 256, 256, 0, stream>>>(z, ss, out);
}

// Round 9
// 747.276 us; speedup vs baseline: 1.0466x; 1.0028x over previous
//
#include <hip/hip_runtime.h>

#define NN 50000
#define NE 400000
#define DIM 256
#define HID 512
#define NL 5
#define BN_EPS 1e-5f
#define NB_SCAN 196   // ceil(NN/256)

typedef float float4v __attribute__((ext_vector_type(4)));
typedef _Float16 half8 __attribute__((ext_vector_type(8)));
typedef _Float16 half4v __attribute__((ext_vector_type(4)));

__device__ __forceinline__ void gl_lds16(const void* g, void* l) {
    __builtin_amdgcn_global_load_lds((__attribute__((address_space(1))) void*)g,
                                     (__attribute__((address_space(3))) void*)l, 16, 0, 0);
}

// ---------------- setup kernels ----------------

__global__ void k_zero(int* p, int n) {
    int i = blockIdx.x * blockDim.x + threadIdx.x;
    if (i < n) p[i] = 0;
}

__global__ void k_x2h(const float* __restrict__ x, _Float16* __restrict__ xh) {
    int i = blockIdx.x * blockDim.x + threadIdx.x;
    if (i >= NN * DIM / 4) return;
    float4 v = ((const float4*)x)[i];
    half4v o;
    o.x = (_Float16)v.x; o.y = (_Float16)v.y; o.z = (_Float16)v.z; o.w = (_Float16)v.w;
    ((half4v*)xh)[i] = o;
}

// C[l][a*3+b][c] = E1[l][a][c] + E2[l][b][c]
__global__ void k_ctab(const float* __restrict__ E1, const float* __restrict__ E2,
                       float* __restrict__ C) {
    int b = blockIdx.x;            // 0..44
    int l = b / 9, ab = b % 9;
    int a = ab / 3, bb = ab % 3;
    int c = threadIdx.x;
    C[(size_t)b * DIM + c] = E1[(size_t)(l * 6 + a) * DIM + c] + E2[(size_t)(l * 3 + bb) * DIM + c];
}

__global__ void k_hist(const int* __restrict__ ei, int* __restrict__ counts) {
    int e = blockIdx.x * blockDim.x + threadIdx.x;
    if (e < NE) atomicAdd(&counts[ei[NE + e]], 1);
}

// ---- multi-block coalesced exclusive scan of counts -> row_ptr/cursor ----
__global__ void k_bsum(const int* __restrict__ counts, int* __restrict__ bsum) {
    __shared__ int s[256];
    int t = threadIdx.x;
    int i = blockIdx.x * 256 + t;
    s[t] = (i < NN) ? counts[i] : 0;
    __syncthreads();
    for (int off = 128; off > 0; off >>= 1) {
        if (t < off) s[t] += s[t + off];
        __syncthreads();
    }
    if (t == 0) bsum[blockIdx.x] = s[0];
}

__global__ void k_bscan(const int* __restrict__ bsum, int* __restrict__ bofs) {
    __shared__ int s[256];
    int t = threadIdx.x;
    int v = (t < NB_SCAN) ? bsum[t] : 0;
    s[t] = v;
    __syncthreads();
    for (int off = 1; off < 256; off <<= 1) {
        int u = (t >= off) ? s[t - off] : 0;
        __syncthreads();
        s[t] += u;
        __syncthreads();
    }
    if (t < NB_SCAN) bofs[t] = s[t] - v;
}

__global__ void k_scatterptr(const int* __restrict__ counts, const int* __restrict__ bofs,
                             int* __restrict__ row_ptr, int* __restrict__ cursor) {
    __shared__ int s[256];
    int t = threadIdx.x;
    int i = blockIdx.x * 256 + t;
    int v = (i < NN) ? counts[i] : 0;
    s[t] = v;
    __syncthreads();
    for (int off = 1; off < 256; off <<= 1) {
        int u = (t >= off) ? s[t - off] : 0;
        __syncthreads();
        s[t] += u;
        __syncthreads();
    }
    if (i < NN) {
        int ex = bofs[blockIdx.x] + s[t] - v;
        row_ptr[i] = ex;
        cursor[i] = ex;
    }
    if (i == NN - 1) row_ptr[NN] = NE;
}

__global__ void k_fill(const int* __restrict__ ei, const int* __restrict__ ea,
                       int* __restrict__ cursor, int* __restrict__ recs) {
    int e = blockIdx.x * blockDim.x + threadIdx.x;
    if (e >= NE) return;
    int src = ei[e];
    int dst = ei[NE + e];
    int a = ea[2 * e];
    int b = ea[2 * e + 1];
    int rec = src | ((a * 3 + b) << 20);
    int pos = atomicAdd(&cursor[dst], 1);
    recs[pos] = rec;
}

// transpose + f16 convert: W [L][K][N] fp32 -> T [L][N][K] f16
__global__ void k_wt(const float* __restrict__ W, _Float16* __restrict__ T, int K, int N) {
    __shared__ float t[32][33];
    int l = blockIdx.z;
    int k0 = blockIdx.y * 32, n0 = blockIdx.x * 32;
    int tx = threadIdx.x, ty = threadIdx.y;   // (32,8)
    const float* Wl = W + (size_t)l * K * N;
    _Float16* Tl = T + (size_t)l * N * K;
    for (int d = 0; d < 32; d += 8)
        t[ty + d][tx] = Wl[(size_t)(k0 + ty + d) * N + n0 + tx];
    __syncthreads();
    for (int d = 0; d < 32; d += 8)
        Tl[(size_t)(n0 + ty + d) * K + k0 + tx] = (_Float16)t[tx][ty + d];
}

// ---------------- aggregation: one wave per node (frozen — round-6 analysis:
// VALU-issue-bound at ~12 fp32 ops/edge/lane floor; Ctab in LDS; masked 4-wide
// ILP batches; f16 accumulate rejected on precision margin) ----------------
template <bool APPLY>
__global__ __launch_bounds__(256) void k_agg(const _Float16* __restrict__ rows,
                                             const float* __restrict__ ss,
                                             const float* __restrict__ Cl,
                                             const int* __restrict__ row_ptr,
                                             const int* __restrict__ recs,
                                             _Float16* __restrict__ aggh) {
    __shared__ __align__(16) float lC[9 * DIM];   // 9 KB edge-combo table
    {
        for (int i = threadIdx.x; i < 576; i += 256)
            ((float4*)lC)[i] = ((const float4*)Cl)[i];
    }
    int node = (blockIdx.x * blockDim.x + threadIdx.x) >> 6;
    int lane = threadIdx.x & 63;
    bool act = node < NN;
    int c = lane * 4;
    int e0 = 0, e1 = 0;
    float s0 = 1.f, s1 = 1.f, s2 = 1.f, s3 = 1.f, t0 = 0.f, t1 = 0.f, t2 = 0.f, t3 = 0.f;
    half4v sv = {0, 0, 0, 0};
    if (act) {
        e0 = row_ptr[node];
        e1 = row_ptr[node + 1];
        if (APPLY) {
            s0 = ss[c]; s1 = ss[c + 1]; s2 = ss[c + 2]; s3 = ss[c + 3];
            t0 = ss[DIM + c]; t1 = ss[DIM + c + 1]; t2 = ss[DIM + c + 2]; t3 = ss[DIM + c + 3];
        }
        sv = *(const half4v*)(rows + (size_t)node * DIM + c);
    }
    __syncthreads();
    if (!act) return;

    float4 cv0 = *(const float4*)(lC + c);   // self-loop attr = (0,0) -> combo 0
    float ax, ay, az, aw;
    if (APPLY) {
        ax = fmaxf((float)sv.x * s0 + t0, 0.f) + cv0.x;
        ay = fmaxf((float)sv.y * s1 + t1, 0.f) + cv0.y;
        az = fmaxf((float)sv.z * s2 + t2, 0.f) + cv0.z;
        aw = fmaxf((float)sv.w * s3 + t3, 0.f) + cv0.w;
    } else {
        ax = (float)sv.x + cv0.x;
        ay = (float)sv.y + cv0.y;
        az = (float)sv.z + cv0.z;
        aw = (float)sv.w + cv0.w;
    }

    int ec = e1 - 1;
    for (int e = e0; e < e1; e += 4) {
        int i1 = min(e + 1, ec), i2 = min(e + 2, ec), i3 = min(e + 3, ec);
        float v1 = (e + 1 <= ec) ? 1.f : 0.f;
        float v2 = (e + 2 <= ec) ? 1.f : 0.f;
        float v3 = (e + 3 <= ec) ? 1.f : 0.f;
        int r0 = recs[e], r1 = recs[i1], r2 = recs[i2], r3 = recs[i3];
        half4v h0 = *(const half4v*)(rows + (size_t)(r0 & 0xFFFFF) * DIM + c);
        half4v h1 = *(const half4v*)(rows + (size_t)(r1 & 0xFFFFF) * DIM + c);
        half4v h2 = *(const half4v*)(rows + (size_t)(r2 & 0xFFFFF) * DIM + c);
        half4v h3 = *(const half4v*)(rows + (size_t)(r3 & 0xFFFFF) * DIM + c);
        float4 c0 = *(const float4*)(lC + (r0 >> 20) * DIM + c);
        float4 c1 = *(const float4*)(lC + (r1 >> 20) * DIM + c);
        float4 c2 = *(const float4*)(lC + (r2 >> 20) * DIM + c);
        float4 c3 = *(const float4*)(lC + (r3 >> 20) * DIM + c);
        if (APPLY) {
            ax += fmaxf((float)h0.x * s0 + t0, 0.f) + c0.x;
            ay += fmaxf((float)h0.y * s1 + t1, 0.f) + c0.y;
            az += fmaxf((float)h0.z * s2 + t2, 0.f) + c0.z;
            aw += fmaxf((float)h0.w * s3 + t3, 0.f) + c0.w;
            ax = fmaf(v1, fmaxf((float)h1.x * s0 + t0, 0.f) + c1.x, ax);
            ay = fmaf(v1, fmaxf((float)h1.y * s1 + t1, 0.f) + c1.y, ay);
            az = fmaf(v1, fmaxf((float)h1.z * s2 + t2, 0.f) + c1.z, az);
            aw = fmaf(v1, fmaxf((float)h1.w * s3 + t3, 0.f) + c1.w, aw);
            ax = fmaf(v2, fmaxf((float)h2.x * s0 + t0, 0.f) + c2.x, ax);
            ay = fmaf(v2, fmaxf((float)h2.y * s1 + t1, 0.f) + c2.y, ay);
            az = fmaf(v2, fmaxf((float)h2.z * s2 + t2, 0.f) + c2.z, az);
            aw = fmaf(v2, fmaxf((float)h2.w * s3 + t3, 0.f) + c2.w, aw);
            ax = fmaf(v3, fmaxf((float)h3.x * s0 + t0, 0.f) + c3.x, ax);
            ay = fmaf(v3, fmaxf((float)h3.y * s1 + t1, 0.f) + c3.y, ay);
            az = fmaf(v3, fmaxf((float)h3.z * s2 + t2, 0.f) + c3.z, az);
            aw = fmaf(v3, fmaxf((float)h3.w * s3 + t3, 0.f) + c3.w, aw);
        } else {
            ax += (float)h0.x + c0.x;
            ay += (float)h0.y + c0.y;
            az += (float)h0.z + c0.z;
            aw += (float)h0.w + c0.w;
            ax = fmaf(v1, (float)h1.x + c1.x, ax);
            ay = fmaf(v1, (float)h1.y + c1.y, ay);
            az = fmaf(v1, (float)h1.z + c1.z, az);
            aw = fmaf(v1, (float)h1.w + c1.w, aw);
            ax = fmaf(v2, (float)h2.x + c2.x, ax);
            ay = fmaf(v2, (float)h2.y + c2.y, ay);
            az = fmaf(v2, (float)h2.z + c2.z, az);
            aw = fmaf(v2, (float)h2.w + c2.w, aw);
            ax = fmaf(v3, (float)h3.x + c3.x, ax);
            ay = fmaf(v3, (float)h3.y + c3.y, ay);
            az = fmaf(v3, (float)h3.z + c3.z, az);
            aw = fmaf(v3, (float)h3.w + c3.w, aw);
        }
    }
    half4v o;
    o.x = (_Float16)ax; o.y = (_Float16)ay; o.z = (_Float16)az; o.w = (_Float16)aw;
    *(half4v*)(aggh + (size_t)node * DIM + c) = o;
}

// ---------------- fused MLP: Z = (relu(A@W1+b1))@W2 + b2, + BN stats ----------------
// Round-9: round-8 pipeline + spill fix. Round-8 post-mortem: the stage-2
// prologue loads (p0..p3) were HOISTED by the scheduler above the H-write loop
// (independent ops), making them co-live with the dying acc1 (64 regs) ->
// peak > 128-reg cap of (512,4) -> ~15MB scratch (WRITE 26.5->37.5MB).
// Fix 1: sched_barrier(0) between H-write and the prologue loads — they still
// issue before __syncthreads (one vmcnt(0) drain pays 4 latencies) but cannot
// float above the H-write. Junction peak = p(32)+addr, acc1 dead.
// Fix 2: stage-1 depth-2 bf ring (bf0/bf1, +16 regs): load qq+2 issues right
// after step qq consumes its buffer -> ~1.5 steps (~200cy) cover per load
// (was 0; bf single-buffer was WAR-serialized). Stage-1 peak:
// acc1(64)+bf0(16)+bf1(16)+af(16)+addr ~ 127 <= 128.
__global__ __launch_bounds__(512, 4) void k_mlp(const _Float16* __restrict__ A,
                                                const _Float16* __restrict__ W1t,
                                                const float* __restrict__ b1,
                                                const _Float16* __restrict__ W2t,
                                                const float* __restrict__ b2,
                                                _Float16* __restrict__ Z,
                                                float* __restrict__ stats, int M) {
    __shared__ _Float16 ldsA[64 * 128];   // 16 KB (A k-chunk, swizzled)
    __shared__ _Float16 ldsH[64 * 512];   // 64 KB (H tile; reused as Z tile)
    int tid = threadIdx.x;
    int w = tid >> 6, lane = tid & 63;    // w: 0..7
    int lm = lane & 15, lg = lane >> 4;
    int row0 = blockIdx.x * 64;

    // ---------- stage 1 ----------
    const float4v zero = {0.f, 0.f, 0.f, 0.f};
    float4v acc1[4][4];
#pragma unroll
    for (int i = 0; i < 4; ++i)
#pragma unroll
        for (int j = 0; j < 4; ++j) acc1[i][j] = zero;

    auto s1_load = [&](half8 (&pb)[4], int kc, int qq) {
#pragma unroll
        for (int nt = 0; nt < 4; ++nt) {
            int n = w * 64 + nt * 16 + lm;
            pb[nt] = *(const half8*)(W1t + (size_t)n * DIM + kc * 128 + qq * 32 + lg * 8);
        }
    };
    auto s1_step = [&](half8 (&pb)[4], int qq) {
        half8 af[4];
#pragma unroll
        for (int mt = 0; mt < 4; ++mt) {
            int m = mt * 16 + lm;
            int slot = qq * 4 + lg;
            af[mt] = *(const half8*)(ldsA + m * 128 + ((slot ^ (m & 7)) * 8));
        }
#pragma unroll
        for (int mt = 0; mt < 4; ++mt)
#pragma unroll
            for (int nt = 0; nt < 4; ++nt)
                acc1[mt][nt] = __builtin_amdgcn_mfma_f32_16x16x32_f16(af[mt], pb[nt],
                                                                      acc1[mt][nt], 0, 0, 0);
    };

    half8 bf0[4], bf1[4];
#pragma unroll
    for (int kc = 0; kc < 2; ++kc) {
        // stage A chunk: 64 rows x 128 k. Wave w stages rows w*8..w*8+7.
        {
            int srow = lane >> 4;      // 0..3
            int slot = lane & 15;      // 16B slot within 128-f16 row
#pragma unroll
            for (int j = 0; j < 2; ++j) {
                int cr = w * 8 + j * 4 + srow;
                int gr = min(row0 + cr, M - 1);
                int gk = kc * 128 + ((slot ^ (cr & 7)) * 8);
                gl_lds16(A + (size_t)gr * DIM + gk, ldsA + (w * 8 + j * 4) * 128);
            }
        }
        s1_load(bf0, kc, 0);   // in flight across the barrier's vmcnt(0) drain
        __syncthreads();
        s1_load(bf1, kc, 1);   // issue before consuming bf0
        s1_step(bf0, 0);
        s1_load(bf0, kc, 2);   // WAR ok: bf0 consumed by step 0
        s1_step(bf1, 1);
        s1_load(bf1, kc, 3);
        s1_step(bf0, 2);
        s1_step(bf1, 3);
        __syncthreads();
    }

    // H (relu) -> ldsH, f16, XOR-swizzled by row (C-layout: col=lm, row=lg*4+r)
#pragma unroll
    for (int nt = 0; nt < 4; ++nt) {
        int col = w * 64 + nt * 16 + lm;
        float bv = b1[col];
        int cs = col >> 3, ci = col & 7;
#pragma unroll
        for (int mt = 0; mt < 4; ++mt)
#pragma unroll
            for (int r = 0; r < 4; ++r) {
                int row = mt * 16 + lg * 4 + r;
                float v = fmaxf(acc1[mt][nt][r] + bv, 0.f);
                ldsH[row * 512 + ((cs ^ (row & 7)) << 3) + ci] = (_Float16)v;
            }
    }

    // ---------- stage 2 (depth-4 software-pipelined W2t loads) ----------
    float4v acc2[4][2];
#pragma unroll
    for (int i = 0; i < 4; ++i)
#pragma unroll
        for (int j = 0; j < 2; ++j) acc2[i][j] = zero;

    auto s2_load = [&](half8 (&pb)[2], int q) {
#pragma unroll
        for (int nt = 0; nt < 2; ++nt) {
            int n = w * 32 + nt * 16 + lm;
            pb[nt] = *(const half8*)(W2t + (size_t)n * HID + q * 32 + lg * 8);
        }
    };
    auto s2_step = [&](half8 (&pb)[2], int q) {
        half8 af[4];
#pragma unroll
        for (int mt = 0; mt < 4; ++mt) {
            int m = mt * 16 + lm;
            int slot = q * 4 + lg;                 // 0..63
            af[mt] = *(const half8*)(ldsH + m * 512 + ((slot ^ (m & 7)) << 3));
        }
#pragma unroll
        for (int mt = 0; mt < 4; ++mt)
#pragma unroll
            for (int nt = 0; nt < 2; ++nt)
                acc2[mt][nt] = __builtin_amdgcn_mfma_f32_16x16x32_f16(af[mt], pb[nt],
                                                                      acc2[mt][nt], 0, 0, 0);
    };

    half8 p0[2], p1[2], p2[2], p3[2];
    // sched fence: prologue loads must NOT hoist above the H-write (acc1 still
    // live there -> round-8's spill). They still issue before the barrier.
    __builtin_amdgcn_sched_barrier(0);
    s2_load(p0, 0); s2_load(p1, 1); s2_load(p2, 2); s2_load(p3, 3);
    __syncthreads();   // H visible
    s2_step(p0, 0);  s2_load(p0, 4);
    s2_step(p1, 1);  s2_load(p1, 5);
    s2_step(p2, 2);  s2_load(p2, 6);
    s2_step(p3, 3);  s2_load(p3, 7);
    s2_step(p0, 4);  s2_load(p0, 8);
    s2_step(p1, 5);  s2_load(p1, 9);
    s2_step(p2, 6);  s2_load(p2, 10);
    s2_step(p3, 7);  s2_load(p3, 11);
    s2_step(p0, 8);  s2_load(p0, 12);
    s2_step(p1, 9);  s2_load(p1, 13);
    s2_step(p2, 10); s2_load(p2, 14);
    s2_step(p3, 11); s2_load(p3, 15);
    s2_step(p0, 12);
    s2_step(p1, 13);
    s2_step(p2, 14);
    s2_step(p3, 15);
    __syncthreads();   // ldsH free -> reuse as Z tile

    // ---------- epilogue: bias + stats + z via LDS transpose ----------
    _Float16* ldsZ = ldsH;   // 64 x 256 f16, swizzled
    float psum[2], psq[2];
#pragma unroll
    for (int nt = 0; nt < 2; ++nt) { psum[nt] = 0.f; psq[nt] = 0.f; }
#pragma unroll
    for (int nt = 0; nt < 2; ++nt) {
        int col = w * 32 + nt * 16 + lm;
        float bv = b2[col];
        int cs = col >> 3, ci = col & 7;
#pragma unroll
        for (int mt = 0; mt < 4; ++mt)
#pragma unroll
            for (int r = 0; r < 4; ++r) {
                int row = mt * 16 + lg * 4 + r;
                float v = acc2[mt][nt][r] + bv;
                if (row0 + row < M) {
                    psum[nt] += v;
                    psq[nt] += v * v;
                }
                ldsZ[row * 256 + ((cs ^ (row & 7)) << 3) + ci] = (_Float16)v;
            }
    }
#pragma unroll
    for (int nt = 0; nt < 2; ++nt) {
        psum[nt] += __shfl_xor(psum[nt], 16);
        psum[nt] += __shfl_xor(psum[nt], 32);
        psq[nt] += __shfl_xor(psq[nt], 16);
        psq[nt] += __shfl_xor(psq[nt], 32);
    }
    if (lg == 0) {
#pragma unroll
        for (int nt = 0; nt < 2; ++nt) {
            int ch = w * 32 + nt * 16 + lm;
            atomicAdd(&stats[ch], psum[nt]);
            atomicAdd(&stats[DIM + ch], psq[nt]);
        }
    }
    __syncthreads();
    // coalesced store: 2048 16B-slots, thread t -> slots t, t+512, ...
#pragma unroll
    for (int i = 0; i < 4; ++i) {
        int s = i * 512 + tid;
        int row = s >> 5, c16 = s & 31;
        if (row0 + row < M) {
            half8 v = *(const half8*)(ldsZ + row * 256 + ((c16 ^ (row & 7)) << 3));
            *(half8*)(Z + (size_t)(row0 + row) * DIM + c16 * 8) = v;
        }
    }
}

// ---------------- BatchNorm finalize (also re-zeros stats) + final output ----------------
__global__ void k_bnfin(float* __restrict__ stats, const float* __restrict__ gamma,
                        const float* __restrict__ beta, float* __restrict__ ss) {
    int c = threadIdx.x;
    float mu = stats[c] * (1.0f / NN);
    float var = stats[DIM + c] * (1.0f / NN) - mu * mu;
    float sc = gamma[c] / sqrtf(var + BN_EPS);
    ss[c] = sc;
    ss[DIM + c] = beta[c] - mu * sc;
    stats[c] = 0.f;
    stats[DIM + c] = 0.f;
}

__global__ void k_out(const _Float16* __restrict__ z, const float* __restrict__ ss,
                      float* __restrict__ out) {
    int i = blockIdx.x * blockDim.x + threadIdx.x;
    if (i >= NN * DIM / 4) return;
    int c4 = (i & (DIM / 4 - 1)) * 4;
    half4v v = ((const half4v*)z)[i];
    float4 o;
    o.x = (float)v.x * ss[c4] + ss[DIM + c4];
    o.y = (float)v.y * ss[c4 + 1] + ss[DIM + c4 + 1];
    o.z = (float)v.z * ss[c4 + 2] + ss[DIM + c4 + 2];
    o.w = (float)v.w * ss[c4 + 3] + ss[DIM + c4 + 3];
    ((float4*)out)[i] = o;
}

// ---------------- host launcher ----------------
extern "C" void kernel_launch(void* const* d_in, const int* in_sizes, int n_in,
                              void* d_out, int out_size, void* d_ws, size_t ws_size,
                              hipStream_t stream) {
    const float* x = (const float*)d_in[0];
    const int* ei = (const int*)d_in[1];
    const int* ea = (const int*)d_in[2];
    const float* W1 = (const float*)d_in[4];
    const float* b1 = (const float*)d_in[5];
    const float* W2 = (const float*)d_in[6];
    const float* b2 = (const float*)d_in[7];
    const float* E1 = (const float*)d_in[8];
    const float* E2 = (const float*)d_in[9];
    const float* gamma = (const float*)d_in[10];
    const float* beta = (const float*)d_in[11];
    float* out = (float*)d_out;

    char* w = (char*)d_ws;
    _Float16* xh = (_Float16*)w;   w += (size_t)NN * DIM * 2;
    _Float16* z = (_Float16*)w;    w += (size_t)NN * DIM * 2;
    _Float16* aggh = (_Float16*)w; w += (size_t)NN * DIM * 2;
    _Float16* W1t = (_Float16*)w;  w += (size_t)NL * DIM * HID * 2;
    _Float16* W2t = (_Float16*)w;  w += (size_t)NL * HID * DIM * 2;
    float* Ctab = (float*)w;       w += (size_t)NL * 9 * DIM * 4;
    float* stats = (float*)w;      w += 2 * DIM * 4;
    float* ss = (float*)w;         w += 2 * DIM * 4;
    int* row_ptr = (int*)w;        w += (size_t)(NN + 2) * 4;
    int* counts = (int*)w;         w += (size_t)NN * 4;
    int* cursor = (int*)w;         w += (size_t)NN * 4;
    int* bsum = (int*)w;           w += 256 * 4;
    int* bofs = (int*)w;           w += 256 * 4;
    int* recs = (int*)w;           w += (size_t)NE * 4;

    // setup: f16 x, edge-combo tables, CSR by dst, transposed f16 weights
    k_zero<<<(NN + 255) / 256, 256, 0, stream>>>(counts, NN);
    k_zero<<<2, 256, 0, stream>>>((int*)stats, 2 * DIM);
    k_x2h<<<(NN * DIM / 4 + 255) / 256, 256, 0, stream>>>(x, xh);
    k_ctab<<<NL * 9, 256, 0, stream>>>(E1, E2, Ctab);
    k_hist<<<(NE + 255) / 256, 256, 0, stream>>>(ei, counts);
    k_bsum<<<NB_SCAN, 256, 0, stream>>>(counts, bsum);
    k_bscan<<<1, 256, 0, stream>>>(bsum, bofs);
    k_scatterptr<<<NB_SCAN, 256, 0, stream>>>(counts, bofs, row_ptr, cursor);
    k_fill<<<(NE + 255) / 256, 256, 0, stream>>>(ei, ea, cursor, recs);
    {
        dim3 b(32, 8);
        dim3 g1(HID / 32, DIM / 32, NL);
        k_wt<<<g1, b, 0, stream>>>(W1, W1t, DIM, HID);
        dim3 g2(DIM / 32, HID / 32, NL);
        k_wt<<<g2, b, 0, stream>>>(W2, W2t, HID, DIM);
    }

    for (int l = 0; l < NL; ++l) {
        const float* Cl = Ctab + (size_t)l * 9 * DIM;
        if (l == 0)
            k_agg<false><<<(NN + 3) / 4, 256, 0, stream>>>(xh, ss, Cl, row_ptr, recs, aggh);
        else
            k_agg<true><<<(NN + 3) / 4, 256, 0, stream>>>(z, ss, Cl, row_ptr, recs, aggh);

        k_mlp<<<(NN + 63) / 64, 512, 0, stream>>>(aggh, W1t + (size_t)l * DIM * HID,
                                                  b1 + (size_t)l * HID,
                                                  W2t + (size_t)l * HID * DIM,
                                                  b2 + (size_t)l * DIM, z, stats, NN);

        k_bnfin<<<1, 256, 0, stream>>>(stats, gamma + (size_t)l * DIM, beta + (size_t)l * DIM, ss);
    }
    k_out<<<(NN * DIM / 4 + 255) / 256, 256, 0, stream>>>(z, ss, out);
}